// Round 1
// baseline (304.382 us; speedup 1.0000x reference)
//
#include <hip/hip_runtime.h>
#include <math.h>

#define BQ 4096
#define DD 256
#define NNEG 32768
#define TILE 64

// ws layout (floats): [0,4096) row_sum | [4096,8192) col_sum | [8192,12288) diag
//                     [12288,16384) offsets (int32)

__device__ __forceinline__ float get_inv_tau(const float* __restrict__ lt) {
  float tau = expf(lt[0]);
  tau = fminf(fmaxf(tau, 1e-4f), 1.0f);
  return 1.0f / tau;
}

// ---------- exclusive scan of n_counts (B=4096, one block) ----------
__global__ __launch_bounds__(1024) void scan_kernel(const int* __restrict__ counts,
                                                    int* __restrict__ offsets) {
  __shared__ int s[1024];
  const int t = threadIdx.x;
  const int c0 = counts[4 * t + 0], c1 = counts[4 * t + 1];
  const int c2 = counts[4 * t + 2], c3 = counts[4 * t + 3];
  const int sum = c0 + c1 + c2 + c3;
  s[t] = sum;
  __syncthreads();
  for (int off = 1; off < 1024; off <<= 1) {
    const int v = (t >= off) ? s[t - off] : 0;
    __syncthreads();
    s[t] += v;
    __syncthreads();
  }
  const int excl = s[t] - sum;  // exclusive prefix of this thread's chunk
  offsets[4 * t + 0] = excl;
  offsets[4 * t + 1] = excl + c0;
  offsets[4 * t + 2] = excl + c0 + c1;
  offsets[4 * t + 3] = excl + c0 + c1 + c2;
}

// ---------- fused sim = q@p^T / tau; accumulate exp row/col sums + diag ----------
// grid (64,64), block 256. 64x64 tile, 4x4 micro-tile per thread.
__global__ __launch_bounds__(256) void sim_kernel(
    const float* __restrict__ q, const float* __restrict__ p,
    const float* __restrict__ logtau,
    float* __restrict__ row_sum, float* __restrict__ col_sum,
    float* __restrict__ diag) {
  // pad=65: inner-loop A reads broadcast (4 addrs), B reads 2-way aliased (free, m136)
  __shared__ float As[TILE][65];
  __shared__ float Bs[TILE][65];
  __shared__ float rs[TILE];
  __shared__ float cs[TILE];

  const int tid = threadIdx.x;
  const int tx = tid & 15;        // 0..15 -> 4 output cols
  const int ty = tid >> 4;        // 0..15 -> 4 output rows
  const int brow = blockIdx.y * TILE;
  const int bcol = blockIdx.x * TILE;
  const float inv_tau = get_inv_tau(logtau);

  if (tid < TILE) { rs[tid] = 0.0f; cs[tid] = 0.0f; }

  float acc[4][4];
#pragma unroll
  for (int i = 0; i < 4; ++i)
#pragma unroll
    for (int j = 0; j < 4; ++j) acc[i][j] = 0.0f;

  const int lr = tid >> 2;  // 0..63 : row within tile for loading
  const int lc = tid & 3;   // 0..3  : float4-column group

  for (int k0 = 0; k0 < DD; k0 += TILE) {
    __syncthreads();
#pragma unroll
    for (int m = 0; m < 4; ++m) {
      const int kk = (lc + 4 * m) * 4;
      const float4 av = *reinterpret_cast<const float4*>(&q[(brow + lr) * DD + k0 + kk]);
      const float4 bv = *reinterpret_cast<const float4*>(&p[(bcol + lr) * DD + k0 + kk]);
      As[lr][kk + 0] = av.x; As[lr][kk + 1] = av.y; As[lr][kk + 2] = av.z; As[lr][kk + 3] = av.w;
      Bs[lr][kk + 0] = bv.x; Bs[lr][kk + 1] = bv.y; Bs[lr][kk + 2] = bv.z; Bs[lr][kk + 3] = bv.w;
    }
    __syncthreads();
#pragma unroll 8
    for (int kk = 0; kk < TILE; ++kk) {
      const float a0 = As[ty * 4 + 0][kk];
      const float a1 = As[ty * 4 + 1][kk];
      const float a2 = As[ty * 4 + 2][kk];
      const float a3 = As[ty * 4 + 3][kk];
      const float b0 = Bs[tx * 4 + 0][kk];
      const float b1 = Bs[tx * 4 + 1][kk];
      const float b2 = Bs[tx * 4 + 2][kk];
      const float b3 = Bs[tx * 4 + 3][kk];
      acc[0][0] += a0 * b0; acc[0][1] += a0 * b1; acc[0][2] += a0 * b2; acc[0][3] += a0 * b3;
      acc[1][0] += a1 * b0; acc[1][1] += a1 * b1; acc[1][2] += a1 * b2; acc[1][3] += a1 * b3;
      acc[2][0] += a2 * b0; acc[2][1] += a2 * b1; acc[2][2] += a2 * b2; acc[2][3] += a2 * b3;
      acc[3][0] += a3 * b0; acc[3][1] += a3 * b1; acc[3][2] += a3 * b2; acc[3][3] += a3 * b3;
    }
  }

  // epilogue: exp, accumulate per-tile row/col sums in LDS, capture diagonal
  float colp[4] = {0.0f, 0.0f, 0.0f, 0.0f};
#pragma unroll
  for (int i = 0; i < 4; ++i) {
    float rowp = 0.0f;
    const int gr = brow + ty * 4 + i;
#pragma unroll
    for (int j = 0; j < 4; ++j) {
      const int gc = bcol + tx * 4 + j;
      const float sv = acc[i][j] * inv_tau;
      const float e = __expf(sv);
      rowp += e;
      colp[j] += e;
      if (gr == gc) diag[gr] = sv;
    }
    atomicAdd(&rs[ty * 4 + i], rowp);
  }
#pragma unroll
  for (int j = 0; j < 4; ++j) atomicAdd(&cs[tx * 4 + j], colp[j]);
  __syncthreads();
  if (tid < TILE) {
    atomicAdd(&row_sum[brow + tid], rs[tid]);
    atomicAdd(&col_sum[bcol + tid], cs[tid]);
  }
}

// ---------- ragged negatives: one wave per query, <=16 dot products ----------
__global__ __launch_bounds__(256) void neg_kernel(
    const float* __restrict__ q, const float* __restrict__ n_emb,
    const int* __restrict__ counts, const int* __restrict__ offsets,
    const float* __restrict__ logtau, float* __restrict__ row_sum) {
  const int gw = (int)((blockIdx.x * blockDim.x + threadIdx.x) >> 6);  // query idx
  const int lane = threadIdx.x & 63;
  if (gw >= BQ) return;
  const float inv_tau = get_inv_tau(logtau);
  const float4 qv = *reinterpret_cast<const float4*>(&q[gw * DD + lane * 4]);
  const int cnt = counts[gw];
  const int off = offsets[gw];
  float acc = 0.0f;
  for (int k = 0; k < cnt; ++k) {
    const float4 nv = *reinterpret_cast<const float4*>(&n_emb[(size_t)(off + k) * DD + lane * 4]);
    float d = qv.x * nv.x + qv.y * nv.y + qv.z * nv.z + qv.w * nv.w;
    d += __shfl_xor(d, 32);
    d += __shfl_xor(d, 16);
    d += __shfl_xor(d, 8);
    d += __shfl_xor(d, 4);
    d += __shfl_xor(d, 2);
    d += __shfl_xor(d, 1);
    acc += __expf(d * inv_tau);
  }
  if (lane == 0 && cnt > 0) atomicAdd(&row_sum[gw], acc);
}

// ---------- finalize: loss = (1/2B) * sum_i(log r_i + log c_i - 2 diag_i) ----------
__global__ __launch_bounds__(1024) void finalize_kernel(
    const float* __restrict__ row_sum, const float* __restrict__ col_sum,
    const float* __restrict__ diag, float* __restrict__ out) {
  __shared__ float s[1024];
  const int t = threadIdx.x;
  float v = 0.0f;
#pragma unroll
  for (int m = 0; m < 4; ++m) {
    const int i = t * 4 + m;
    v += logf(row_sum[i]) + logf(col_sum[i]) - 2.0f * diag[i];
  }
  s[t] = v;
  __syncthreads();
  for (int off = 512; off >= 1; off >>= 1) {
    if (t < off) s[t] += s[t + off];
    __syncthreads();
  }
  if (t == 0) out[0] = s[0] / (2.0f * BQ);
}

extern "C" void kernel_launch(void* const* d_in, const int* in_sizes, int n_in,
                              void* d_out, int out_size, void* d_ws, size_t ws_size,
                              hipStream_t stream) {
  const float* q      = (const float*)d_in[0];
  const float* p      = (const float*)d_in[1];
  const float* n_emb  = (const float*)d_in[2];
  const int*   counts = (const int*)d_in[3];
  const float* logtau = (const float*)d_in[4];
  float* out = (float*)d_out;

  float* ws      = (float*)d_ws;
  float* row_sum = ws;
  float* col_sum = ws + BQ;
  float* diag    = ws + 2 * BQ;
  int*   offsets = (int*)(ws + 3 * BQ);

  // zero the atomically-accumulated buffers (ws is poisoned 0xAA each call)
  hipMemsetAsync(row_sum, 0, 2 * BQ * sizeof(float), stream);

  scan_kernel<<<1, 1024, 0, stream>>>(counts, offsets);
  sim_kernel<<<dim3(TILE, TILE), 256, 0, stream>>>(q, p, logtau, row_sum, col_sum, diag);
  neg_kernel<<<BQ * 64 / 256, 256, 0, stream>>>(q, n_emb, counts, offsets, logtau, row_sum);
  finalize_kernel<<<1, 1024, 0, stream>>>(row_sum, col_sum, diag, out);
}

// Round 2
// 143.377 us; speedup vs baseline: 2.1230x; 2.1230x over previous
//
#include <hip/hip_runtime.h>
#include <math.h>

#define BQ 4096
#define DD 256
#define NNEG 32768

typedef __bf16 bf16x8 __attribute__((ext_vector_type(8)));
typedef float f32x4 __attribute__((ext_vector_type(4)));

// ws layout:
//   float row_sum[4096] | float col_sum[4096] | float diag[4096] | int offsets[4096]
//   ushort q_bf[4096*256] | ushort p_bf[4096*256]

__device__ __forceinline__ float get_inv_tau(const float* __restrict__ lt) {
  float tau = __expf(lt[0]);
  tau = fminf(fmaxf(tau, 1e-4f), 1.0f);
  return 1.0f / tau;
}

__device__ __forceinline__ unsigned int f2bf(float f) {
  unsigned int u = __float_as_uint(f);
  u += 0x7FFFu + ((u >> 16) & 1u);  // round-to-nearest-even
  return u >> 16;
}

// ---------- convert q,p (f32) -> bf16 (as ushort) ----------
__global__ __launch_bounds__(256) void cvt_kernel(const float* __restrict__ q,
                                                  const float* __restrict__ p,
                                                  ushort* __restrict__ qb,
                                                  ushort* __restrict__ pb) {
  const int i = blockIdx.x * 256 + threadIdx.x;  // 0..262143, 8 elems each
  const int half = (BQ * DD) / 8;                // 131072
  const float* src = (i < half) ? q : p;
  ushort* dst = (i < half) ? qb : pb;
  const int idx = (i < half) ? i : (i - half);
  const float4 a = *reinterpret_cast<const float4*>(&src[idx * 8]);
  const float4 b = *reinterpret_cast<const float4*>(&src[idx * 8 + 4]);
  uint4 o;
  o.x = f2bf(a.x) | (f2bf(a.y) << 16);
  o.y = f2bf(a.z) | (f2bf(a.w) << 16);
  o.z = f2bf(b.x) | (f2bf(b.y) << 16);
  o.w = f2bf(b.z) | (f2bf(b.w) << 16);
  *reinterpret_cast<uint4*>(&dst[idx * 8]) = o;
}

// ---------- exclusive scan of n_counts (one block, wave-shfl based) ----------
__global__ __launch_bounds__(1024) void scan_kernel(const int* __restrict__ counts,
                                                    int* __restrict__ offsets) {
  __shared__ int wtot[16], wexc[16];
  const int t = threadIdx.x;
  const int wid = t >> 6, lane = t & 63;
  const int4 c = reinterpret_cast<const int4*>(counts)[t];
  const int s = c.x + c.y + c.z + c.w;
  int x = s;
#pragma unroll
  for (int off = 1; off < 64; off <<= 1) {
    int v = __shfl_up(x, off);
    if (lane >= off) x += v;
  }
  if (lane == 63) wtot[wid] = x;
  __syncthreads();
  if (wid == 0) {
    int orig = (lane < 16) ? wtot[lane] : 0;
    int wv = orig;
#pragma unroll
    for (int off = 1; off < 16; off <<= 1) {
      int v = __shfl_up(wv, off);
      if (lane >= off) wv += v;
    }
    if (lane < 16) wexc[lane] = wv - orig;
  }
  __syncthreads();
  const int excl = x - s + wexc[wid];
  offsets[4 * t + 0] = excl;
  offsets[4 * t + 1] = excl + c.x;
  offsets[4 * t + 2] = excl + c.x + c.y;
  offsets[4 * t + 3] = excl + c.x + c.y + c.z;
}

// ---------- fused bf16-MFMA sim = q@p^T/tau, exp, row/col sums, diag ----------
// grid (32,32), block 256 = 4 waves (2x2), each wave 64x64 output.
__global__ __launch_bounds__(256) void sim_kernel(
    const ushort* __restrict__ qb, const ushort* __restrict__ pb,
    const float* __restrict__ logtau,
    float* __restrict__ row_sum, float* __restrict__ col_sum,
    float* __restrict__ diag) {
  const int tid = threadIdx.x;
  const int lane = tid & 63;
  const int wv = tid >> 6;        // 0..3
  const int wr = wv >> 1, wc = wv & 1;
  const int lrow = lane >> 4;     // 0..3 (k-group for A/B, row-group for C)
  const int lcol = lane & 15;     // 0..15 (row for A / col for B, col for C)
  const float inv_tau = get_inv_tau(logtau);

  const int arow0 = blockIdx.y * 128 + wr * 64;  // wave's A row base
  const int bcol0 = blockIdx.x * 128 + wc * 64;  // wave's B col base

  const ushort* aptr = qb + (size_t)(arow0 + lcol) * DD + lrow * 8;
  const ushort* bptr = pb + (size_t)(bcol0 + lcol) * DD + lrow * 8;

  f32x4 acc[4][4];
#pragma unroll
  for (int i = 0; i < 4; ++i)
#pragma unroll
    for (int j = 0; j < 4; ++j) acc[i][j] = (f32x4){0.f, 0.f, 0.f, 0.f};

#pragma unroll 2
  for (int k0 = 0; k0 < DD; k0 += 32) {
    bf16x8 a[4], b[4];
#pragma unroll
    for (int m = 0; m < 4; ++m)
      a[m] = *reinterpret_cast<const bf16x8*>(aptr + (size_t)m * 16 * DD + k0);
#pragma unroll
    for (int n = 0; n < 4; ++n)
      b[n] = *reinterpret_cast<const bf16x8*>(bptr + (size_t)n * 16 * DD + k0);
#pragma unroll
    for (int m = 0; m < 4; ++m)
#pragma unroll
      for (int n = 0; n < 4; ++n)
        acc[m][n] = __builtin_amdgcn_mfma_f32_16x16x32_bf16(a[m], b[n], acc[m][n], 0, 0, 0);
  }

  // epilogue: exp + reductions
  float colp[4] = {0.f, 0.f, 0.f, 0.f};
#pragma unroll
  for (int mi = 0; mi < 4; ++mi) {
    float rowp[4] = {0.f, 0.f, 0.f, 0.f};
#pragma unroll
    for (int ni = 0; ni < 4; ++ni) {
      const f32x4 v = acc[mi][ni];
#pragma unroll
      for (int r = 0; r < 4; ++r) {
        const float sv = v[r] * inv_tau;
        const float e = __expf(sv);
        const int gr = arow0 + mi * 16 + lrow * 4 + r;
        const int gc = bcol0 + ni * 16 + lcol;
        if (gr == gc) diag[gr] = sv;
        rowp[r] += e;
        colp[ni] += e;
      }
    }
#pragma unroll
    for (int r = 0; r < 4; ++r) {
      float x = rowp[r];
      x += __shfl_xor(x, 1);
      x += __shfl_xor(x, 2);
      x += __shfl_xor(x, 4);
      x += __shfl_xor(x, 8);
      if (lcol == 0) atomicAdd(&row_sum[arow0 + mi * 16 + lrow * 4 + r], x);
    }
  }
#pragma unroll
  for (int ni = 0; ni < 4; ++ni) {
    float x = colp[ni];
    x += __shfl_xor(x, 16);
    x += __shfl_xor(x, 32);
    if (lrow == 0) atomicAdd(&col_sum[bcol0 + ni * 16 + lcol], x);
  }
}

// ---------- ragged negatives: one wave per query, 16 groups x 4 lanes ----------
__global__ __launch_bounds__(256) void neg_kernel(
    const float* __restrict__ q, const float* __restrict__ n_emb,
    const int* __restrict__ counts, const int* __restrict__ offsets,
    const float* __restrict__ logtau, float* __restrict__ row_sum) {
  const int gw = (blockIdx.x * 256 + threadIdx.x) >> 6;
  const int lane = threadIdx.x & 63;
  const int g = lane >> 2, sl = lane & 3;
  const float inv_tau = get_inv_tau(logtau);
  const int cnt = counts[gw];
  const int off = offsets[gw];
  float d = 0.f;
  if (g < cnt) {
    const float4* nrow = reinterpret_cast<const float4*>(n_emb + (size_t)(off + g) * DD);
    const float4* qrow = reinterpret_cast<const float4*>(q + (size_t)gw * DD);
#pragma unroll
    for (int t = 0; t < 16; ++t) {
      const float4 nv = nrow[sl + 4 * t];
      const float4 qv = qrow[sl + 4 * t];
      d += qv.x * nv.x + qv.y * nv.y + qv.z * nv.z + qv.w * nv.w;
    }
  }
  d += __shfl_xor(d, 1);
  d += __shfl_xor(d, 2);
  float val = (sl == 0 && g < cnt) ? __expf(d * inv_tau) : 0.f;
  val += __shfl_xor(val, 4);
  val += __shfl_xor(val, 8);
  val += __shfl_xor(val, 16);
  val += __shfl_xor(val, 32);
  if (lane == 0 && val != 0.f) atomicAdd(&row_sum[gw], val);
}

// ---------- finalize ----------
__global__ __launch_bounds__(1024) void finalize_kernel(
    const float* __restrict__ row_sum, const float* __restrict__ col_sum,
    const float* __restrict__ diag, float* __restrict__ out) {
  __shared__ float ws[16];
  const int t = threadIdx.x;
  const int wid = t >> 6, lane = t & 63;
  const float4 r = reinterpret_cast<const float4*>(row_sum)[t];
  const float4 c = reinterpret_cast<const float4*>(col_sum)[t];
  const float4 d = reinterpret_cast<const float4*>(diag)[t];
  float v = __logf(r.x) + __logf(r.y) + __logf(r.z) + __logf(r.w)
          + __logf(c.x) + __logf(c.y) + __logf(c.z) + __logf(c.w)
          - 2.f * (d.x + d.y + d.z + d.w);
  v += __shfl_xor(v, 1);
  v += __shfl_xor(v, 2);
  v += __shfl_xor(v, 4);
  v += __shfl_xor(v, 8);
  v += __shfl_xor(v, 16);
  v += __shfl_xor(v, 32);
  if (lane == 0) ws[wid] = v;
  __syncthreads();
  if (wid == 0) {
    float x = (lane < 16) ? ws[lane] : 0.f;
    x += __shfl_xor(x, 1);
    x += __shfl_xor(x, 2);
    x += __shfl_xor(x, 4);
    x += __shfl_xor(x, 8);
    if (lane == 0) out[0] = x / (2.0f * BQ);
  }
}

extern "C" void kernel_launch(void* const* d_in, const int* in_sizes, int n_in,
                              void* d_out, int out_size, void* d_ws, size_t ws_size,
                              hipStream_t stream) {
  const float* q      = (const float*)d_in[0];
  const float* p      = (const float*)d_in[1];
  const float* n_emb  = (const float*)d_in[2];
  const int*   counts = (const int*)d_in[3];
  const float* logtau = (const float*)d_in[4];
  float* out = (float*)d_out;

  float* ws      = (float*)d_ws;
  float* row_sum = ws;
  float* col_sum = ws + BQ;
  float* diag    = ws + 2 * BQ;
  int*   offsets = (int*)(ws + 3 * BQ);
  ushort* qb     = (ushort*)(ws + 4 * BQ);
  ushort* pb     = qb + (size_t)BQ * DD;

  hipMemsetAsync(row_sum, 0, 2 * BQ * sizeof(float), stream);

  cvt_kernel<<<1024, 256, 0, stream>>>(q, p, qb, pb);
  scan_kernel<<<1, 1024, 0, stream>>>(counts, offsets);
  sim_kernel<<<dim3(32, 32), 256, 0, stream>>>(qb, pb, logtau, row_sum, col_sum, diag);
  neg_kernel<<<BQ * 64 / 256, 256, 0, stream>>>(q, n_emb, counts, offsets, logtau, row_sum);
  finalize_kernel<<<1, 1024, 0, stream>>>(row_sum, col_sum, diag, out);
}

// Round 3
// 138.259 us; speedup vs baseline: 2.2015x; 1.0370x over previous
//
#include <hip/hip_runtime.h>
#include <math.h>

#define BQ 4096
#define DD 256
#define NNEG 32768

typedef __bf16 bf16x8 __attribute__((ext_vector_type(8)));
typedef float f32x4 __attribute__((ext_vector_type(4)));

typedef const __attribute__((address_space(1))) void GvPtr;
typedef __attribute__((address_space(3))) void LdsPtr;

// ws layout:
//   float row_sum[4096] | float col_sum[4096] | float diag[4096] |
//   int owner[32768] | ushort qb[4096*256] | ushort pb[4096*256]

__device__ __forceinline__ float get_inv_tau(const float* __restrict__ lt) {
  float tau = __expf(lt[0]);
  tau = fminf(fmaxf(tau, 1e-4f), 1.0f);
  return 1.0f / tau;
}

__device__ __forceinline__ unsigned int f2bf(float f) {
  unsigned int u = __float_as_uint(f);
  u += 0x7FFFu + ((u >> 16) & 1u);  // round-to-nearest-even
  return u >> 16;
}

// ---------- fused: blocks 0..1023 convert q,p -> bf16; block 1024 does
// zero-init of row/col sums + count-scan + owner scatter ----------
__global__ __launch_bounds__(256) void cvtscan_kernel(
    const float* __restrict__ q, const float* __restrict__ p,
    const int* __restrict__ counts,
    ushort* __restrict__ qb, ushort* __restrict__ pb,
    int* __restrict__ owner, float* __restrict__ rowcol /* 8192 floats */) {
  __shared__ int wtot[4];
  const int t = threadIdx.x;
  if (blockIdx.x < 1024) {
    const int i = blockIdx.x * 256 + t;  // 8 elems each
    const int half = (BQ * DD) / 8;      // 131072
    const float* src = (i < half) ? q : p;
    ushort* dst = (i < half) ? qb : pb;
    const int idx = (i < half) ? i : (i - half);
    const float4 a = *reinterpret_cast<const float4*>(&src[idx * 8]);
    const float4 b = *reinterpret_cast<const float4*>(&src[idx * 8 + 4]);
    uint4 o;
    o.x = f2bf(a.x) | (f2bf(a.y) << 16);
    o.y = f2bf(a.z) | (f2bf(a.w) << 16);
    o.z = f2bf(b.x) | (f2bf(b.y) << 16);
    o.w = f2bf(b.z) | (f2bf(b.w) << 16);
    *reinterpret_cast<uint4*>(&dst[idx * 8]) = o;
    return;
  }
  // ---- scan block ----
  const int wid = t >> 6, lane = t & 63;
  const float4 z = {0.f, 0.f, 0.f, 0.f};
#pragma unroll
  for (int i = 0; i < 8; ++i) reinterpret_cast<float4*>(rowcol)[t * 8 + i] = z;

  int cl[16];
  int s = 0;
#pragma unroll
  for (int i = 0; i < 4; ++i) {
    const int4 c = reinterpret_cast<const int4*>(counts)[t * 4 + i];
    cl[4 * i + 0] = c.x; cl[4 * i + 1] = c.y; cl[4 * i + 2] = c.z; cl[4 * i + 3] = c.w;
    s += c.x + c.y + c.z + c.w;
  }
  int x = s;
#pragma unroll
  for (int off = 1; off < 64; off <<= 1) {
    const int v = __shfl_up(x, off);
    if (lane >= off) x += v;
  }
  if (lane == 63) wtot[wid] = x;
  __syncthreads();
  int base = 0;
  for (int w = 0; w < wid; ++w) base += wtot[w];
  int running = base + x - s;  // exclusive prefix for this thread's 16 queries
#pragma unroll
  for (int k = 0; k < 16; ++k) {
    const int qi = 16 * t + k;
    for (int e = 0; e < cl[k]; ++e) owner[running + e] = qi;
    running += cl[k];
  }
}

// ---------- sim: 128x128 tile, 4 waves (2x2), BK=64 double-buffered LDS,
// global_load_lds staging, 2-phase pipeline, fused exp/row/col/diag ----------
__global__ __launch_bounds__(256) void sim_kernel(
    const ushort* __restrict__ qb, const ushort* __restrict__ pb,
    const float* __restrict__ logtau,
    float* __restrict__ row_sum, float* __restrict__ col_sum,
    float* __restrict__ diag) {
  __shared__ ushort As[2][128 * 64];
  __shared__ ushort Bs[2][128 * 64];

  const int tid = threadIdx.x;
  const int lane = tid & 63;
  const int wv = tid >> 6;
  const int wr = wv >> 1, wc = wv & 1;
  const int lrow = lane >> 4;   // 0..3
  const int lcol = lane & 15;   // 0..15

  // XCD-aware swizzle: 1024 blocks, 128 consecutive per XCD
  const int bid = (int)blockIdx.x;
  const int swz = (bid & 7) * 128 + (bid >> 3);
  const int bx = swz & 31, by = swz >> 5;
  const int brow = by * 128, bcol = bx * 128;

  const float inv_tau = get_inv_tau(logtau);

  // staging coords: thread covers 16B at row (i*32 + r), col c (bf16)
  const int sr = tid >> 3;        // 0..31
  const int sc = (tid & 7) * 8;   // 0,8,..,56

  f32x4 acc[4][4];
#pragma unroll
  for (int i = 0; i < 4; ++i)
#pragma unroll
    for (int j = 0; j < 4; ++j) acc[i][j] = (f32x4){0.f, 0.f, 0.f, 0.f};

#define STAGE(buf, k0)                                                          \
  {                                                                             \
    _Pragma("unroll")                                                           \
    for (int i = 0; i < 4; ++i) {                                               \
      const ushort* ga = qb + (size_t)(brow + i * 32 + sr) * DD + (k0) + sc;    \
      __builtin_amdgcn_global_load_lds((GvPtr*)ga,                              \
          (LdsPtr*)(&As[buf][0] + i * 2048 + tid * 8), 16, 0, 0);               \
    }                                                                           \
    _Pragma("unroll")                                                           \
    for (int i = 0; i < 4; ++i) {                                               \
      const ushort* gb = pb + (size_t)(bcol + i * 32 + sr) * DD + (k0) + sc;    \
      __builtin_amdgcn_global_load_lds((GvPtr*)gb,                              \
          (LdsPtr*)(&Bs[buf][0] + i * 2048 + tid * 8), 16, 0, 0);               \
    }                                                                           \
  }

  STAGE(0, 0);
  __syncthreads();

#pragma unroll
  for (int t = 0; t < 4; ++t) {
    if (t < 3) STAGE((t + 1) & 1, (t + 1) * 64);
    const ushort* lA = &As[t & 1][0];
    const ushort* lB = &Bs[t & 1][0];
#pragma unroll
    for (int sub = 0; sub < 2; ++sub) {
      const int kb = sub * 32 + lrow * 8;
      bf16x8 a[4], b[4];
#pragma unroll
      for (int m = 0; m < 4; ++m)
        a[m] = *reinterpret_cast<const bf16x8*>(lA + (wr * 64 + m * 16 + lcol) * 64 + kb);
#pragma unroll
      for (int n = 0; n < 4; ++n)
        b[n] = *reinterpret_cast<const bf16x8*>(lB + (wc * 64 + n * 16 + lcol) * 64 + kb);
#pragma unroll
      for (int m = 0; m < 4; ++m)
#pragma unroll
        for (int n = 0; n < 4; ++n)
          acc[m][n] = __builtin_amdgcn_mfma_f32_16x16x32_bf16(a[m], b[n], acc[m][n], 0, 0, 0);
    }
    __syncthreads();
  }
#undef STAGE

  // epilogue: exp + row/col reductions + diag
  const int arow0 = brow + wr * 64;
  const int bcol0 = bcol + wc * 64;
  float colp[4] = {0.f, 0.f, 0.f, 0.f};
#pragma unroll
  for (int mi = 0; mi < 4; ++mi) {
    float rowp[4] = {0.f, 0.f, 0.f, 0.f};
#pragma unroll
    for (int ni = 0; ni < 4; ++ni) {
      const f32x4 v = acc[mi][ni];
#pragma unroll
      for (int r = 0; r < 4; ++r) {
        const float sv = v[r] * inv_tau;
        const float e = __expf(sv);
        const int gr = arow0 + mi * 16 + lrow * 4 + r;
        const int gc = bcol0 + ni * 16 + lcol;
        if (gr == gc) diag[gr] = sv;
        rowp[r] += e;
        colp[ni] += e;
      }
    }
#pragma unroll
    for (int r = 0; r < 4; ++r) {
      float x = rowp[r];
      x += __shfl_xor(x, 1);
      x += __shfl_xor(x, 2);
      x += __shfl_xor(x, 4);
      x += __shfl_xor(x, 8);
      if (lcol == 0) atomicAdd(&row_sum[arow0 + mi * 16 + lrow * 4 + r], x);
    }
  }
#pragma unroll
  for (int ni = 0; ni < 4; ++ni) {
    float x = colp[ni];
    x += __shfl_xor(x, 16);
    x += __shfl_xor(x, 32);
    if (lrow == 0) atomicAdd(&col_sum[bcol0 + ni * 16 + lcol], x);
  }
}

// ---------- negatives: one 4-lane group per negative (dense, owner-mapped) ----------
__global__ __launch_bounds__(256) void neg_kernel(
    const float* __restrict__ q, const float* __restrict__ n_emb,
    const int* __restrict__ owner, const float* __restrict__ logtau,
    float* __restrict__ row_sum) {
  const int j = blockIdx.x * 64 + (threadIdx.x >> 2);  // negative id
  const int sl = threadIdx.x & 3;
  const float inv_tau = get_inv_tau(logtau);
  const int ow = owner[j];
  const float4* nrow = reinterpret_cast<const float4*>(n_emb + (size_t)j * DD);
  const float4* qrow = reinterpret_cast<const float4*>(q + (size_t)ow * DD);
  float d = 0.f;
#pragma unroll
  for (int t = 0; t < 16; ++t) {
    const float4 nv = nrow[sl + 4 * t];
    const float4 qv = qrow[sl + 4 * t];
    d += qv.x * nv.x + qv.y * nv.y + qv.z * nv.z + qv.w * nv.w;
  }
  d += __shfl_xor(d, 1);
  d += __shfl_xor(d, 2);
  if (sl == 0) atomicAdd(&row_sum[ow], __expf(d * inv_tau));
}

// ---------- finalize ----------
__global__ __launch_bounds__(1024) void finalize_kernel(
    const float* __restrict__ row_sum, const float* __restrict__ col_sum,
    const float* __restrict__ diag, float* __restrict__ out) {
  __shared__ float ws[16];
  const int t = threadIdx.x;
  const int wid = t >> 6, lane = t & 63;
  const float4 r = reinterpret_cast<const float4*>(row_sum)[t];
  const float4 c = reinterpret_cast<const float4*>(col_sum)[t];
  const float4 d = reinterpret_cast<const float4*>(diag)[t];
  float v = __logf(r.x) + __logf(r.y) + __logf(r.z) + __logf(r.w)
          + __logf(c.x) + __logf(c.y) + __logf(c.z) + __logf(c.w)
          - 2.f * (d.x + d.y + d.z + d.w);
  v += __shfl_xor(v, 1);
  v += __shfl_xor(v, 2);
  v += __shfl_xor(v, 4);
  v += __shfl_xor(v, 8);
  v += __shfl_xor(v, 16);
  v += __shfl_xor(v, 32);
  if (lane == 0) ws[wid] = v;
  __syncthreads();
  if (wid == 0) {
    float x = (lane < 16) ? ws[lane] : 0.f;
    x += __shfl_xor(x, 1);
    x += __shfl_xor(x, 2);
    x += __shfl_xor(x, 4);
    x += __shfl_xor(x, 8);
    if (lane == 0) out[0] = x / (2.0f * BQ);
  }
}

extern "C" void kernel_launch(void* const* d_in, const int* in_sizes, int n_in,
                              void* d_out, int out_size, void* d_ws, size_t ws_size,
                              hipStream_t stream) {
  const float* q      = (const float*)d_in[0];
  const float* p      = (const float*)d_in[1];
  const float* n_emb  = (const float*)d_in[2];
  const int*   counts = (const int*)d_in[3];
  const float* logtau = (const float*)d_in[4];
  float* out = (float*)d_out;

  float* ws      = (float*)d_ws;
  float* row_sum = ws;            // [4096]
  float* col_sum = ws + BQ;       // [4096]
  float* diag    = ws + 2 * BQ;   // [4096]
  int*   owner   = (int*)(ws + 3 * BQ);           // [32768]
  ushort* qb     = (ushort*)(owner + NNEG);       // [4096*256]
  ushort* pb     = qb + (size_t)BQ * DD;          // [4096*256]

  cvtscan_kernel<<<1025, 256, 0, stream>>>(q, p, counts, qb, pb, owner, row_sum);
  neg_kernel<<<NNEG / 64, 256, 0, stream>>>(q, n_emb, owner, logtau, row_sum);
  sim_kernel<<<1024, 256, 0, stream>>>(qb, pb, logtau, row_sum, col_sum, diag);
  finalize_kernel<<<1, 1024, 0, stream>>>(row_sum, col_sum, diag, out);
}

// Round 4
// 137.803 us; speedup vs baseline: 2.2088x; 1.0033x over previous
//
#include <hip/hip_runtime.h>
#include <math.h>

#define BQ 4096
#define DD 256
#define NNEG 32768

typedef __bf16 bf16x8 __attribute__((ext_vector_type(8)));
typedef float f32x4 __attribute__((ext_vector_type(4)));

typedef const __attribute__((address_space(1))) void GvPtr;
typedef __attribute__((address_space(3))) void LdsPtr;

// ws layout:
//   float row_sum[4096] | float col_sum[4096] | float diag[4096] |
//   int owner[32768] | ushort qb[4096*256] | ushort pb[4096*256]

__device__ __forceinline__ float get_inv_tau(const float* __restrict__ lt) {
  float tau = __expf(lt[0]);
  tau = fminf(fmaxf(tau, 1e-4f), 1.0f);
  return 1.0f / tau;
}

__device__ __forceinline__ unsigned int f2bf(float f) {
  unsigned int u = __float_as_uint(f);
  u += 0x7FFFu + ((u >> 16) & 1u);  // round-to-nearest-even
  return u >> 16;
}

// ---------- fused: blocks 0..1023 convert q,p -> bf16; block 1024 does
// zero-init of row/col sums + count-scan + owner scatter ----------
__global__ __launch_bounds__(256) void cvtscan_kernel(
    const float* __restrict__ q, const float* __restrict__ p,
    const int* __restrict__ counts,
    ushort* __restrict__ qb, ushort* __restrict__ pb,
    int* __restrict__ owner, float* __restrict__ rowcol /* 8192 floats */) {
  __shared__ int wtot[4];
  const int t = threadIdx.x;
  if (blockIdx.x < 1024) {
    const int i = blockIdx.x * 256 + t;  // 8 elems each
    const int half = (BQ * DD) / 8;      // 131072
    const float* src = (i < half) ? q : p;
    ushort* dst = (i < half) ? qb : pb;
    const int idx = (i < half) ? i : (i - half);
    const float4 a = *reinterpret_cast<const float4*>(&src[idx * 8]);
    const float4 b = *reinterpret_cast<const float4*>(&src[idx * 8 + 4]);
    uint4 o;
    o.x = f2bf(a.x) | (f2bf(a.y) << 16);
    o.y = f2bf(a.z) | (f2bf(a.w) << 16);
    o.z = f2bf(b.x) | (f2bf(b.y) << 16);
    o.w = f2bf(b.z) | (f2bf(b.w) << 16);
    *reinterpret_cast<uint4*>(&dst[idx * 8]) = o;
    return;
  }
  // ---- scan block ----
  const int wid = t >> 6, lane = t & 63;
  const float4 z = {0.f, 0.f, 0.f, 0.f};
#pragma unroll
  for (int i = 0; i < 8; ++i) reinterpret_cast<float4*>(rowcol)[t * 8 + i] = z;

  int cl[16];
  int s = 0;
#pragma unroll
  for (int i = 0; i < 4; ++i) {
    const int4 c = reinterpret_cast<const int4*>(counts)[t * 4 + i];
    cl[4 * i + 0] = c.x; cl[4 * i + 1] = c.y; cl[4 * i + 2] = c.z; cl[4 * i + 3] = c.w;
    s += c.x + c.y + c.z + c.w;
  }
  int x = s;
#pragma unroll
  for (int off = 1; off < 64; off <<= 1) {
    const int v = __shfl_up(x, off);
    if (lane >= off) x += v;
  }
  if (lane == 63) wtot[wid] = x;
  __syncthreads();
  int base = 0;
  for (int w = 0; w < wid; ++w) base += wtot[w];
  int running = base + x - s;  // exclusive prefix for this thread's 16 queries
#pragma unroll
  for (int k = 0; k < 16; ++k) {
    const int qi = 16 * t + k;
    for (int e = 0; e < cl[k]; ++e) owner[running + e] = qi;
    running += cl[k];
  }
}

// ---------- fused sim + neg dispatch ----------
// blocks [0,1024): sim 128x128 tile, 4 waves (2x2), BK=32 double-buffered LDS
//                  (32KB -> 4 blocks/CU), global_load_lds staging, fused
//                  exp/row/col/diag epilogue.
// blocks [1024,2048): negatives, 8 lanes per negative, owner-mapped.
__global__ __launch_bounds__(256) void simneg_kernel(
    const ushort* __restrict__ qb, const ushort* __restrict__ pb,
    const float* __restrict__ q, const float* __restrict__ n_emb,
    const int* __restrict__ owner, const float* __restrict__ logtau,
    float* __restrict__ row_sum, float* __restrict__ col_sum,
    float* __restrict__ diag) {
  __shared__ ushort As[2][128 * 32];
  __shared__ ushort Bs[2][128 * 32];

  const int tid = threadIdx.x;
  const float inv_tau = get_inv_tau(logtau);
  const int bid = (int)blockIdx.x;

  if (bid >= 1024) {
    // ---------------- negatives ----------------
    const int j = (bid - 1024) * 32 + (tid >> 3);  // negative id
    const int sl = tid & 7;
    const int ow = owner[j];
    const float4* nrow = reinterpret_cast<const float4*>(n_emb + (size_t)j * DD);
    const float4* qrow = reinterpret_cast<const float4*>(q + (size_t)ow * DD);
    float d0 = 0.f, d1 = 0.f;
#pragma unroll
    for (int t = 0; t < 8; t += 2) {
      const float4 n0 = nrow[sl + 8 * t];
      const float4 q0 = qrow[sl + 8 * t];
      const float4 n1 = nrow[sl + 8 * (t + 1)];
      const float4 q1 = qrow[sl + 8 * (t + 1)];
      d0 += q0.x * n0.x + q0.y * n0.y + q0.z * n0.z + q0.w * n0.w;
      d1 += q1.x * n1.x + q1.y * n1.y + q1.z * n1.z + q1.w * n1.w;
    }
    float d = d0 + d1;
    d += __shfl_xor(d, 1);
    d += __shfl_xor(d, 2);
    d += __shfl_xor(d, 4);
    if (sl == 0) atomicAdd(&row_sum[ow], __expf(d * inv_tau));
    return;
  }

  // ---------------- sim tile ----------------
  const int lane = tid & 63;
  const int wv = tid >> 6;
  const int wr = wv >> 1, wc = wv & 1;
  const int lrow = lane >> 4;   // 0..3
  const int lcol = lane & 15;   // 0..15

  // XCD-aware swizzle: 1024 sim blocks, 128 consecutive per XCD
  const int swz = (bid & 7) * 128 + (bid >> 3);
  const int bx = swz & 31, by = swz >> 5;
  const int brow = by * 128, bcol = bx * 128;

  // staging coords: thread covers 16B at row (i*64 + sr), bf16 col sc
  const int sr = tid >> 2;        // 0..63
  const int sc = (tid & 3) * 8;   // 0,8,16,24

  f32x4 acc[4][4];
#pragma unroll
  for (int i = 0; i < 4; ++i)
#pragma unroll
    for (int j = 0; j < 4; ++j) acc[i][j] = (f32x4){0.f, 0.f, 0.f, 0.f};

#define STAGE(buf, k0)                                                          \
  {                                                                             \
    _Pragma("unroll")                                                           \
    for (int i = 0; i < 2; ++i) {                                               \
      const ushort* ga = qb + (size_t)(brow + i * 64 + sr) * DD + (k0) + sc;    \
      __builtin_amdgcn_global_load_lds((GvPtr*)ga,                              \
          (LdsPtr*)(&As[buf][0] + i * 2048 + tid * 8), 16, 0, 0);               \
      const ushort* gb = pb + (size_t)(bcol + i * 64 + sr) * DD + (k0) + sc;    \
      __builtin_amdgcn_global_load_lds((GvPtr*)gb,                              \
          (LdsPtr*)(&Bs[buf][0] + i * 2048 + tid * 8), 16, 0, 0);               \
    }                                                                           \
  }

  STAGE(0, 0);
  __syncthreads();

#pragma unroll
  for (int t = 0; t < 8; ++t) {
    if (t < 7) STAGE((t + 1) & 1, (t + 1) * 32);
    const ushort* lA = &As[t & 1][0];
    const ushort* lB = &Bs[t & 1][0];
    bf16x8 a[4], b[4];
#pragma unroll
    for (int m = 0; m < 4; ++m)
      a[m] = *reinterpret_cast<const bf16x8*>(lA + (wr * 64 + m * 16 + lcol) * 32 + lrow * 8);
#pragma unroll
    for (int n = 0; n < 4; ++n)
      b[n] = *reinterpret_cast<const bf16x8*>(lB + (wc * 64 + n * 16 + lcol) * 32 + lrow * 8);
#pragma unroll
    for (int m = 0; m < 4; ++m)
#pragma unroll
      for (int n = 0; n < 4; ++n)
        acc[m][n] = __builtin_amdgcn_mfma_f32_16x16x32_bf16(a[m], b[n], acc[m][n], 0, 0, 0);
    __syncthreads();
  }
#undef STAGE

  // epilogue: exp + row/col reductions + diag
  const int arow0 = brow + wr * 64;
  const int bcol0 = bcol + wc * 64;
  float colp[4] = {0.f, 0.f, 0.f, 0.f};
#pragma unroll
  for (int mi = 0; mi < 4; ++mi) {
    float rowp[4] = {0.f, 0.f, 0.f, 0.f};
#pragma unroll
    for (int ni = 0; ni < 4; ++ni) {
      const f32x4 v = acc[mi][ni];
#pragma unroll
      for (int r = 0; r < 4; ++r) {
        const float sv = v[r] * inv_tau;
        const float e = __expf(sv);
        const int gr = arow0 + mi * 16 + lrow * 4 + r;
        const int gc = bcol0 + ni * 16 + lcol;
        if (gr == gc) diag[gr] = sv;
        rowp[r] += e;
        colp[ni] += e;
      }
    }
#pragma unroll
    for (int r = 0; r < 4; ++r) {
      float x = rowp[r];
      x += __shfl_xor(x, 1);
      x += __shfl_xor(x, 2);
      x += __shfl_xor(x, 4);
      x += __shfl_xor(x, 8);
      if (lcol == 0) atomicAdd(&row_sum[arow0 + mi * 16 + lrow * 4 + r], x);
    }
  }
#pragma unroll
  for (int ni = 0; ni < 4; ++ni) {
    float x = colp[ni];
    x += __shfl_xor(x, 16);
    x += __shfl_xor(x, 32);
    if (lrow == 0) atomicAdd(&col_sum[bcol0 + ni * 16 + lcol], x);
  }
}

// ---------- finalize ----------
__global__ __launch_bounds__(1024) void finalize_kernel(
    const float* __restrict__ row_sum, const float* __restrict__ col_sum,
    const float* __restrict__ diag, float* __restrict__ out) {
  __shared__ float ws[16];
  const int t = threadIdx.x;
  const int wid = t >> 6, lane = t & 63;
  const float4 r = reinterpret_cast<const float4*>(row_sum)[t];
  const float4 c = reinterpret_cast<const float4*>(col_sum)[t];
  const float4 d = reinterpret_cast<const float4*>(diag)[t];
  float v = __logf(r.x) + __logf(r.y) + __logf(r.z) + __logf(r.w)
          + __logf(c.x) + __logf(c.y) + __logf(c.z) + __logf(c.w)
          - 2.f * (d.x + d.y + d.z + d.w);
  v += __shfl_xor(v, 1);
  v += __shfl_xor(v, 2);
  v += __shfl_xor(v, 4);
  v += __shfl_xor(v, 8);
  v += __shfl_xor(v, 16);
  v += __shfl_xor(v, 32);
  if (lane == 0) ws[wid] = v;
  __syncthreads();
  if (wid == 0) {
    float x = (lane < 16) ? ws[lane] : 0.f;
    x += __shfl_xor(x, 1);
    x += __shfl_xor(x, 2);
    x += __shfl_xor(x, 4);
    x += __shfl_xor(x, 8);
    if (lane == 0) out[0] = x / (2.0f * BQ);
  }
}

extern "C" void kernel_launch(void* const* d_in, const int* in_sizes, int n_in,
                              void* d_out, int out_size, void* d_ws, size_t ws_size,
                              hipStream_t stream) {
  const float* q      = (const float*)d_in[0];
  const float* p      = (const float*)d_in[1];
  const float* n_emb  = (const float*)d_in[2];
  const int*   counts = (const int*)d_in[3];
  const float* logtau = (const float*)d_in[4];
  float* out = (float*)d_out;

  float* ws      = (float*)d_ws;
  float* row_sum = ws;            // [4096]
  float* col_sum = ws + BQ;       // [4096]
  float* diag    = ws + 2 * BQ;   // [4096]
  int*   owner   = (int*)(ws + 3 * BQ);           // [32768]
  ushort* qb     = (ushort*)(owner + NNEG);       // [4096*256]
  ushort* pb     = qb + (size_t)BQ * DD;          // [4096*256]

  cvtscan_kernel<<<1025, 256, 0, stream>>>(q, p, counts, qb, pb, owner, row_sum);
  simneg_kernel<<<2048, 256, 0, stream>>>(qb, pb, q, n_emb, owner, logtau,
                                          row_sum, col_sum, diag);
  finalize_kernel<<<1, 1024, 0, stream>>>(row_sum, col_sum, diag, out);
}